// Round 6
// baseline (34036.441 us; speedup 1.0000x reference)
//
#include <hip/hip_runtime.h>

// ============ RE-RUN of round-5 experiment (bench infra failed; no data) =====
// Change under test vs round 4: remove the per-step agent-scope ACQUIRE (which
// invalidates L1+L2 on every block every timestep) and instead read the
// remote-written h vectors with relaxed agent-scope atomic loads (served fresh
// from the coherence point, NO cache invalidation). One acquire remains at
// layer entry to cover x=ret and staged weights.

#define B    64
#define T    512
#define H    600
#define G3   1800
#define IN0  300
#define NBLK 150    // 4 j-columns per block (150*4 = 600)
#define NTHR 512    // (bp:32) x (jj:4) x (kh:4) -> 8 waves/CU
#define TCH  16     // timesteps per gi chunk
#define NCHUNK (T / TCH)   // 32
#define KP   672    // padded K for the scan (600 + 72 zeros); quad-aligned kh slices
#define KQ   (KP / 4)      // 168 floats per kh slice = 42 float4
#define KPWH 684    // Wh LDS row stride (2-way b128 aliasing: irreducible at 16 bases)
#define KPW0 312    // Wi LDS row stride L0
#define KPW1 600    // Wi LDS row stride L1

// ---------------- ws layout (floats) ----------------
#define WI0_OFF 0
#define WI0_SZ  (IN0 * G3)
#define WH_SZ   (H * G3)
#define WH0_OFF (WI0_OFF + WI0_SZ)
#define WI1_OFF (WH0_OFF + WH_SZ)
#define WH1_OFF (WI1_OFF + WH_SZ)
#define BC0_OFF (WH1_OFF + WH_SZ)
#define BC1_OFF (BC0_OFF + H * 4)
#define HA_OFF  (BC1_OFF + H * 4)
#define HB_OFF  (HA_OFF + B * KP)          // padded h buffers [B][672]
#define GI_OFF  (HB_OFF + B * KP)
#define GI_SZ   (TCH * B * H * 4)          // gi4: [tl][b][j][4]
#define BAR_OFF (GI_OFF + GI_SZ)           // 256 ints: cnt shards at [s*16], gen at [128+s*16]

// ---- L2-bypassing fresh load: relaxed agent-scope atomic (NO invalidation) ----
// All call sites are 8-byte aligned (KP, KQ, and inner offsets are multiples
// of 2 floats). Lowers to global_load_dwordx2 with coherence bits; no CAS.
__device__ __forceinline__ float4 ldg_f4_agent(const float* p) {
    unsigned long long u0 = __hip_atomic_load((const unsigned long long*)p,
                                              __ATOMIC_RELAXED, __HIP_MEMORY_SCOPE_AGENT);
    unsigned long long u1 = __hip_atomic_load((const unsigned long long*)(p + 2),
                                              __ATOMIC_RELAXED, __HIP_MEMORY_SCOPE_AGENT);
    float4 r;
    r.x = __uint_as_float((unsigned)u0);
    r.y = __uint_as_float((unsigned)(u0 >> 32));
    r.z = __uint_as_float((unsigned)u1);
    r.w = __uint_as_float((unsigned)(u1 >> 32));
    return r;
}

// ---------------- grid barrier v5: sharded RMW arrival, acquire only if ACQ ----
// Arrival: RELEASE fetch_add on shard (blockIdx&7). Detector: lanes 0..7 of
// block 0 RMW-poll the 8 shards, release-store 8 gen shards. Pollers RMW-poll
// their gen shard (RMW executes at coherence point: always fresh, NO cache
// invalidation). ACQ=true additionally does ONE acquire load (L1/L2 invalidate)
// -- used only at layer entry, where plain cached reads of x/ret/W follow.
// Monotone counts = ABA-free. Shard targets: 150 = 6*19 + 2*18.
template<bool ACQ>
__device__ __forceinline__ void grid_barrier(int* __restrict__ bar, int& bno) {
    ++bno;
    __syncthreads();
    if (blockIdx.x == 0) {
        if (threadIdx.x < 64) {
            if (threadIdx.x == 0)
                __hip_atomic_fetch_add(&bar[0], 1, __ATOMIC_RELEASE, __HIP_MEMORY_SCOPE_AGENT);
            const int s = threadIdx.x;
            const int tgt = (s < 8) ? bno * ((s < 6) ? 19 : 18) : 0;
            for (;;) {
                int v = (s < 8)
                    ? __hip_atomic_fetch_add(&bar[s * 16], 0, __ATOMIC_RELAXED, __HIP_MEMORY_SCOPE_AGENT)
                    : 0x7fffffff;
                if (__all(v >= tgt)) break;
                __builtin_amdgcn_s_sleep(1);
            }
            if (threadIdx.x < 8)
                __hip_atomic_store(&bar[128 + threadIdx.x * 16], bno, __ATOMIC_RELEASE, __HIP_MEMORY_SCOPE_AGENT);
            if (ACQ && threadIdx.x == 0)
                (void)__hip_atomic_load(&bar[0], __ATOMIC_ACQUIRE, __HIP_MEMORY_SCOPE_AGENT);
        }
    } else {
        if (threadIdx.x == 0) {
            __hip_atomic_fetch_add(&bar[(blockIdx.x & 7) * 16], 1, __ATOMIC_RELEASE, __HIP_MEMORY_SCOPE_AGENT);
            int* g = &bar[128 + (blockIdx.x & 7) * 16];
            while (__hip_atomic_fetch_add(g, 0, __ATOMIC_RELAXED, __HIP_MEMORY_SCOPE_AGENT) < bno)
                __builtin_amdgcn_s_sleep(1);
            if (ACQ)
                (void)__hip_atomic_load(&bar[0], __ATOMIC_ACQUIRE, __HIP_MEMORY_SCOPE_AGENT);
        }
    }
    __syncthreads();
}

__global__ void init_bar(int* bar) { if (threadIdx.x < 256) bar[threadIdx.x] = 0; }

// Pack W[(g*H+j)][k] -> dst[k][j*3+g]  (k-major, gate-interleaved columns)
__global__ void build_wp(const float* __restrict__ W, float* __restrict__ dst, int kdim) {
    int idx = blockIdx.x * blockDim.x + threadIdx.x;
    if (idx >= kdim * G3) return;
    int k = idx / G3;
    int c = idx - k * G3;
    int j = c / 3;
    int g = c - j * 3;
    dst[idx] = W[(size_t)(g * H + j) * kdim + k];
}

// BC[j] = (bih_r+bhh_r, bih_z+bhh_z, bih_n, bhh_n)
__global__ void build_bc(const float* __restrict__ bih0, const float* __restrict__ bhh0,
                         const float* __restrict__ bih1, const float* __restrict__ bhh1,
                         float* __restrict__ BC0, float* __restrict__ BC1) {
    int j = blockIdx.x * blockDim.x + threadIdx.x;
    if (j >= H) return;
    BC0[j * 4 + 0] = bih0[j] + bhh0[j];
    BC0[j * 4 + 1] = bih0[H + j] + bhh0[H + j];
    BC0[j * 4 + 2] = bih0[2 * H + j];
    BC0[j * 4 + 3] = bhh0[2 * H + j];
    BC1[j * 4 + 0] = bih1[j] + bhh1[j];
    BC1[j * 4 + 1] = bih1[H + j] + bhh1[H + j];
    BC1[j * 4 + 2] = bih1[2 * H + j];
    BC1[j * 4 + 3] = bhh1[2 * H + j];
}

// Dual-batch triple dot over N4 float4s: two h streams read via agent-scope
// bypass loads (fresh, no invalidation), ping-pong double-buffered; shared LDS
// weight quads (each feeds 24 FMAs). Handles odd N4/CH.
template<int N4, int CH>
__device__ __forceinline__ void dot3x2(const float* __restrict__ a0,
                                       const float* __restrict__ a1,
                                       const float* wr, const float* wz, const float* wn,
                                       float& sr0, float& sz0, float& sn0,
                                       float& sr1, float& sz1, float& sn1) {
    constexpr int NCH = N4 / CH;
    static_assert(N4 % CH == 0, "chunking");
    float4 A0[CH], A1[CH], B0[CH], B1[CH];
    #pragma unroll
    for (int i = 0; i < CH; ++i) {
        A0[i] = ldg_f4_agent(a0 + i * 4);
        A1[i] = ldg_f4_agent(a1 + i * 4);
    }
    #pragma unroll 1
    for (int c = 0; c < NCH; c += 2) {
        if (c + 1 < NCH) {
            #pragma unroll
            for (int i = 0; i < CH; ++i) {
                B0[i] = ldg_f4_agent(a0 + ((c + 1) * CH + i) * 4);
                B1[i] = ldg_f4_agent(a1 + ((c + 1) * CH + i) * 4);
            }
        }
        #pragma unroll
        for (int i = 0; i < CH; ++i) {
            const int k = (c * CH + i) * 4;
            const float4 wR = *(const float4*)(wr + k);
            const float4 wZ = *(const float4*)(wz + k);
            const float4 wN = *(const float4*)(wn + k);
            float4 a = A0[i];
            sr0 += a.x * wR.x + a.y * wR.y + a.z * wR.z + a.w * wR.w;
            sz0 += a.x * wZ.x + a.y * wZ.y + a.z * wZ.z + a.w * wZ.w;
            sn0 += a.x * wN.x + a.y * wN.y + a.z * wN.z + a.w * wN.w;
            a = A1[i];
            sr1 += a.x * wR.x + a.y * wR.y + a.z * wR.z + a.w * wR.w;
            sz1 += a.x * wZ.x + a.y * wZ.y + a.z * wZ.z + a.w * wZ.w;
            sn1 += a.x * wN.x + a.y * wN.y + a.z * wN.z + a.w * wN.w;
        }
        if (c + 1 < NCH) {
            if (c + 2 < NCH) {
                #pragma unroll
                for (int i = 0; i < CH; ++i) {
                    A0[i] = ldg_f4_agent(a0 + ((c + 2) * CH + i) * 4);
                    A1[i] = ldg_f4_agent(a1 + ((c + 2) * CH + i) * 4);
                }
            }
            #pragma unroll
            for (int i = 0; i < CH; ++i) {
                const int k = ((c + 1) * CH + i) * 4;
                const float4 wR = *(const float4*)(wr + k);
                const float4 wZ = *(const float4*)(wz + k);
                const float4 wN = *(const float4*)(wn + k);
                float4 a = B0[i];
                sr0 += a.x * wR.x + a.y * wR.y + a.z * wR.z + a.w * wR.w;
                sz0 += a.x * wZ.x + a.y * wZ.y + a.z * wZ.z + a.w * wZ.w;
                sn0 += a.x * wN.x + a.y * wN.y + a.z * wN.z + a.w * wN.w;
                a = B1[i];
                sr1 += a.x * wR.x + a.y * wR.y + a.z * wR.z + a.w * wR.w;
                sz1 += a.x * wZ.x + a.y * wZ.y + a.z * wZ.z + a.w * wZ.w;
                sn1 += a.x * wN.x + a.y * wN.y + a.z * wN.z + a.w * wN.w;
            }
        }
    }
}

// Input-GEMM inner: 8 consecutive t-rows of one batch vs this thread's 3 gate
// columns. x is layer-local (covered by the layer-entry acquire): PLAIN cached
// loads -- with no per-step invalidates the chunk now stays warm in L2.
template<int KIN>
__device__ __forceinline__ void gemm8(const float* xb,
                                      const float* wr, const float* wz, const float* wn,
                                      float* aR, float* aZ, float* aN) {
    constexpr int N4 = KIN / 4;
    float4 X[8], Y[8];
    #pragma unroll
    for (int i = 0; i < 8; ++i) X[i] = *(const float4*)(xb + (size_t)i * KIN);
    #pragma unroll 1
    for (int c = 0; c < N4; c += 2) {
        if (c + 1 < N4) {
            #pragma unroll
            for (int i = 0; i < 8; ++i) Y[i] = *(const float4*)(xb + (size_t)i * KIN + (c + 1) * 4);
        }
        {
            const int k = c * 4;
            const float4 wR = *(const float4*)(wr + k);
            const float4 wZ = *(const float4*)(wz + k);
            const float4 wN = *(const float4*)(wn + k);
            #pragma unroll
            for (int i = 0; i < 8; ++i) {
                const float4 a = X[i];
                aR[i] += a.x * wR.x + a.y * wR.y + a.z * wR.z + a.w * wR.w;
                aZ[i] += a.x * wZ.x + a.y * wZ.y + a.z * wZ.z + a.w * wZ.w;
                aN[i] += a.x * wN.x + a.y * wN.y + a.z * wN.z + a.w * wN.w;
            }
        }
        if (c + 1 < N4) {
            if (c + 2 < N4) {
                #pragma unroll
                for (int i = 0; i < 8; ++i) X[i] = *(const float4*)(xb + (size_t)i * KIN + (c + 2) * 4);
            }
            const int k = (c + 1) * 4;
            const float4 wR = *(const float4*)(wr + k);
            const float4 wZ = *(const float4*)(wz + k);
            const float4 wN = *(const float4*)(wn + k);
            #pragma unroll
            for (int i = 0; i < 8; ++i) {
                const float4 a = Y[i];
                aR[i] += a.x * wR.x + a.y * wR.y + a.z * wR.z + a.w * wR.w;
                aZ[i] += a.x * wZ.x + a.y * wZ.y + a.z * wZ.z + a.w * wZ.w;
                aN[i] += a.x * wN.x + a.y * wN.y + a.z * wN.z + a.w * wN.w;
            }
        }
    }
}

// x and ret may alias (layer 1) -> both non-restrict.
template<int LAYER>
__device__ void gru_layer(const float* x, const float* __restrict__ hid,
                          const float* __restrict__ WIp, const float* __restrict__ WHp,
                          const float* __restrict__ BC,
                          float* __restrict__ hA, float* __restrict__ hB,
                          float* __restrict__ gi, float* ret, float* __restrict__ outh,
                          float* Wi, float* Wh, int* bar, int& bno) {
    constexpr int KIN  = LAYER ? H : IN0;
    constexpr int KPWI = LAYER ? KPW1 : KPW0;
    const int tid = threadIdx.x;
    const int jj = tid & 3;            // j column within block
    const int kh = (tid >> 2) & 3;     // K-quarter (scan); (batch-half, octet) in GEMM
    const int bp = tid >> 4;           // batch pair 0..31: batches {bp, bp+32}
    const int b0 = bp, b1 = bp + 32;
    const int j  = blockIdx.x * 4 + jj;
    const int wcol0 = blockIdx.x * 12;
    const int bg  = bp + (kh >> 1) * 32;   // GEMM batch 0..63
    const int oct = kh & 1;                // GEMM t-row octet

    // Stage this block's 12 W_ih and 12 zero-padded W_hh gate-columns into LDS.
    for (int idx = tid; idx < 12 * KIN; idx += NTHR) {
        int k = idx / 12, c = idx - k * 12;
        Wi[c * KPWI + k] = WIp[(size_t)k * G3 + wcol0 + c];
    }
    for (int idx = tid; idx < 12 * KP; idx += NTHR) {
        int k = idx / 12, c = idx - k * 12;
        Wh[c * KPWH + k] = (k < H) ? WHp[(size_t)k * G3 + wcol0 + c] : 0.f;
    }
    // h buffers, padded layout [B][KP]; pads MUST be finite (they hit zero weights).
    for (int idx = blockIdx.x * NTHR + tid; idx < B * KP; idx += NBLK * NTHR) {
        int bb = idx / KP, col = idx - bb * KP;
        float v = (col < H) ? hid[bb * H + col] : 0.f;
        __builtin_nontemporal_store(v, &hA[idx]);
        __builtin_nontemporal_store(v, &hB[idx]);
    }
    grid_barrier<true>(bar, bno);   // layer-entry: the ONE acquire this layer
                                    // (covers x=ret + staging; scan uses bypass loads)

    const float4 bc = *(const float4*)(BC + j * 4);
    const float* wrI = &Wi[(jj * 3 + 0) * KPWI];
    const float* wzI = &Wi[(jj * 3 + 1) * KPWI];
    const float* wnI = &Wi[(jj * 3 + 2) * KPWI];
    const float* wrH = &Wh[(jj * 3 + 0) * KPWH + kh * KQ];
    const float* wzH = &Wh[(jj * 3 + 1) * KPWH + kh * KQ];
    const float* wnH = &Wh[(jj * 3 + 2) * KPWH + kh * KQ];

    float hv0 = hid[b0 * H + j];       // recurrent state (kh==0 lanes maintain)
    float hv1 = hid[b1 * H + j];
    float hold0 = 0.f, hold1 = 0.f;    // LAYER 1 lag-write holds

    float* hc = hA;
    float* hn = hB;

    #pragma unroll 1
    for (int ch = 0; ch < NCHUNK; ++ch) {
        const int t0 = ch * TCH;

        // ---- gi GEMM phase: all 512 threads; batch bg, rows t0+oct*8..+7 ----
        {
            float aR[8], aZ[8], aN[8];
            #pragma unroll
            for (int i = 0; i < 8; ++i) { aR[i] = 0.f; aZ[i] = 0.f; aN[i] = 0.f; }
            const float* xb = x + ((size_t)bg * T + t0 + oct * 8) * KIN;
            gemm8<KIN>(xb, wrI, wzI, wnI, aR, aZ, aN);
            #pragma unroll
            for (int i = 0; i < 8; ++i) {
                float4 o;
                o.x = aR[i] + bc.x;   // r pre-activation + both r biases
                o.y = aZ[i] + bc.y;   // z pre-activation + both z biases
                o.z = aN[i] + bc.z;   // n x-part + bih_n
                o.w = bc.w;           // bhh_n (added inside r*(.) in scan)
                *(float4*)(gi + ((size_t)((oct * 8 + i) * B + bg) * H + j) * 4) = o;
            }
        }
        // gi for (b, j) written and read by the SAME block (same L2, no
        // invalidates anymore -> stays warm all chunk) -> block barrier only.
        __syncthreads();

        // ---- scan: 16 sequential steps; thread = 2 batches x K-quarter ----
        #pragma unroll 1
        for (int tl = 0; tl < TCH; ++tl) {
            const int t = t0 + tl;
            float4 g40, g41;
            if (kh == 0) {
                g40 = *(const float4*)(gi + ((size_t)(tl * B + b0) * H + j) * 4);
                g41 = *(const float4*)(gi + ((size_t)(tl * B + b1) * H + j) * 4);
            }
            float sr0 = 0.f, sz0 = 0.f, sn0 = 0.f, sr1 = 0.f, sz1 = 0.f, sn1 = 0.f;
            dot3x2<KQ / 4, 6>(hc + (size_t)b0 * KP + kh * KQ,
                              hc + (size_t)b1 * KP + kh * KQ,
                              wrH, wzH, wnH, sr0, sz0, sn0, sr1, sz1, sn1);
            // combine K-quarters: kh sits in lane bits 2-3 -> butterfly xor 4, 8
            sr0 += __shfl_xor(sr0, 4); sr0 += __shfl_xor(sr0, 8);
            sz0 += __shfl_xor(sz0, 4); sz0 += __shfl_xor(sz0, 8);
            sn0 += __shfl_xor(sn0, 4); sn0 += __shfl_xor(sn0, 8);
            sr1 += __shfl_xor(sr1, 4); sr1 += __shfl_xor(sr1, 8);
            sz1 += __shfl_xor(sz1, 4); sz1 += __shfl_xor(sz1, 8);
            sn1 += __shfl_xor(sn1, 4); sn1 += __shfl_xor(sn1, 8);
            if (kh == 0) {
                float r0 = 1.f / (1.f + __expf(-(sr0 + g40.x)));
                float z0 = 1.f / (1.f + __expf(-(sz0 + g40.y)));
                float n0 = tanhf(g40.z + r0 * (sn0 + g40.w));
                hv0 = (1.f - z0) * n0 + z0 * hv0;
                __builtin_nontemporal_store(hv0, &hn[(size_t)b0 * KP + j]);
                float r1 = 1.f / (1.f + __expf(-(sr1 + g41.x)));
                float z1 = 1.f / (1.f + __expf(-(sz1 + g41.y)));
                float n1 = tanhf(g41.z + r1 * (sn1 + g41.w));
                hv1 = (1.f - z1) * n1 + z1 * hv1;
                __builtin_nontemporal_store(hv1, &hn[(size_t)b1 * KP + j]);
                if (LAYER == 0) {
                    __builtin_nontemporal_store(hv0, &ret[((size_t)b0 * T + t) * H + j]);
                    __builtin_nontemporal_store(hv1, &ret[((size_t)b1 * T + t) * H + j]);
                } else {
                    // lag-write: row t-1 was GEMM-read >= one barrier+dot ago
                    if (t > 0) {
                        __builtin_nontemporal_store(hold0, &ret[((size_t)b0 * T + (t - 1)) * H + j]);
                        __builtin_nontemporal_store(hold1, &ret[((size_t)b1 * T + (t - 1)) * H + j]);
                    }
                    hold0 = hv0; hold1 = hv1;
                }
            }
            grid_barrier<false>(bar, bno);   // h exchange: NO acquire (bypass reads)
            float* tmp = hc; hc = hn; hn = tmp;
        }
    }
    if (kh == 0) {
        if (LAYER == 1) {
            __builtin_nontemporal_store(hold0, &ret[((size_t)b0 * T + (T - 1)) * H + j]);
            __builtin_nontemporal_store(hold1, &ret[((size_t)b1 * T + (T - 1)) * H + j]);
        }
        __builtin_nontemporal_store(hv0, &outh[b0 * H + j]);
        __builtin_nontemporal_store(hv1, &outh[b1 * H + j]);
    }
    grid_barrier<false>(bar, bno);   // ret complete; next layer's entry barrier acquires
}

__global__ void __launch_bounds__(NTHR, 2) gru_main(
    const float* x0, const float* __restrict__ hid,
    const float* __restrict__ WI0, const float* __restrict__ WH0,
    const float* __restrict__ WI1, const float* __restrict__ WH1,
    const float* __restrict__ BC0, const float* __restrict__ BC1,
    float* __restrict__ hA, float* __restrict__ hB, float* __restrict__ gi,
    float* ret, float* __restrict__ outh, int* bar) {
    __shared__ __align__(16) float Wi[12 * KPW1];   // 28,800 B (L0 uses stride KPW0)
    __shared__ __align__(16) float Wh[12 * KPWH];   // 32,832 B -> total 61,632 B
    int bno = 0;
    gru_layer<0>(x0,  hid,         WI0, WH0, BC0, hA, hB, gi, ret, outh,         Wi, Wh, bar, bno);
    gru_layer<1>(ret, hid + B * H, WI1, WH1, BC1, hA, hB, gi, ret, outh + B * H, Wi, Wh, bar, bno);
}

extern "C" void kernel_launch(void* const* d_in, const int* in_sizes, int n_in,
                              void* d_out, int out_size, void* d_ws, size_t ws_size,
                              hipStream_t stream) {
    const float* x0   = (const float*)d_in[0];
    const float* hid  = (const float*)d_in[1];
    const float* Wih0 = (const float*)d_in[2];
    const float* Whh0 = (const float*)d_in[3];
    const float* bih0 = (const float*)d_in[4];
    const float* bhh0 = (const float*)d_in[5];
    const float* Wih1 = (const float*)d_in[6];
    const float* Whh1 = (const float*)d_in[7];
    const float* bih1 = (const float*)d_in[8];
    const float* bhh1 = (const float*)d_in[9];

    float* ws  = (float*)d_ws;
    float* WI0 = ws + WI0_OFF;
    float* WH0 = ws + WH0_OFF;
    float* WI1 = ws + WI1_OFF;
    float* WH1 = ws + WH1_OFF;
    float* BC0 = ws + BC0_OFF;
    float* BC1 = ws + BC1_OFF;
    float* hA  = ws + HA_OFF;
    float* hB  = ws + HB_OFF;
    float* gi  = ws + GI_OFF;
    int*   bar = (int*)(ws + BAR_OFF);

    float* ret  = (float*)d_out;
    float* outh = ret + (size_t)B * T * H;

    build_wp<<<(IN0 * G3 + 255) / 256, 256, 0, stream>>>(Wih0, WI0, IN0);
    build_wp<<<(H * G3 + 255) / 256, 256, 0, stream>>>(Whh0, WH0, H);
    build_wp<<<(H * G3 + 255) / 256, 256, 0, stream>>>(Wih1, WI1, H);
    build_wp<<<(H * G3 + 255) / 256, 256, 0, stream>>>(Whh1, WH1, H);
    build_bc<<<(H + 255) / 256, 256, 0, stream>>>(bih0, bhh0, bih1, bhh1, BC0, BC1);
    init_bar<<<1, 256, 0, stream>>>(bar);

    gru_main<<<dim3(NBLK), dim3(NTHR), 0, stream>>>(
        x0, hid, WI0, WH0, WI1, WH1, BC0, BC1, hA, hB, gi, ret, outh, bar);
}

// Round 7
// 23682.111 us; speedup vs baseline: 1.4372x; 1.4372x over previous
//
#include <hip/hip_runtime.h>

// ============ Round 7: round-4 base (23.4 ms, measured best) + two fixes =====
// (a) Scan weight reads ds_read_b128 -> ds_read_b64 with KPWH=694:
//     per-instruction float-offsets = 2*jj + 8*kh (+even const) = 16 DISTINCT
//     EVEN bank-starts -> conflict-free (b128 could never be: 16 bases > 8
//     four-bank groups; measured 6.2e8 conflict cycles in round 4).
// (b) Barrier arrival shards 8 -> 16 (9-10 serialized RMWs per L3 line).
// Round-6 bypass loads reverted: cached h reads + ONE acquire/step/block won
// by 10.6 ms over L3-direct reads.

#define B    64
#define T    512
#define H    600
#define G3   1800
#define IN0  300
#define NBLK 150    // 4 j-columns per block (150*4 = 600)
#define NTHR 512    // (bp:32) x (jj:4) x (kh:4) -> 8 waves/CU
#define TCH  16     // timesteps per gi chunk
#define NCHUNK (T / TCH)   // 32
#define KP   672    // padded K for the scan (600 + 72 zeros)
#define KQ   (KP / 4)      // 168 floats per kh slice
#define KPWH 694    // Wh LDS row stride: 3*694 % 32 == 2, KQ % 32 == 8 ->
                    // (jj,kh) b64 bases = {0,2,..,30} all even residues: conflict-free
#define KPW0 312    // Wi LDS row stride L0 (3*312 % 32 == 8 -> 4 bcast bases, free)
#define KPW1 600    // Wi LDS row stride L1 (same)

// ---------------- ws layout (floats) ----------------
#define WI0_OFF 0
#define WI0_SZ  (IN0 * G3)
#define WH_SZ   (H * G3)
#define WH0_OFF (WI0_OFF + WI0_SZ)
#define WI1_OFF (WH0_OFF + WH_SZ)
#define WH1_OFF (WI1_OFF + WH_SZ)
#define BC0_OFF (WH1_OFF + WH_SZ)
#define BC1_OFF (BC0_OFF + H * 4)
#define HA_OFF  (BC1_OFF + H * 4)
#define HB_OFF  (HA_OFF + B * KP)          // padded h buffers [B][672]
#define GI_OFF  (HB_OFF + B * KP)
#define GI_SZ   (TCH * B * H * 4)          // gi4: [tl][b][j][4]
#define BAR_OFF (GI_OFF + GI_SZ)           // 512 ints: cnt[s*16] s<16, gen[256+s*16]

// ---------------- grid barrier v6: 16-shard RMW arrival, per-step acquire ------
// Arrival: RELEASE fetch_add on shard (blockIdx&15) -> 9-10 serialized RMWs per
// L3 line, 16 lines in parallel. Detector: lanes 0..15 of block 0 RMW-poll the
// shards (RMW executes at coherence point: fresh, no invalidation), then
// release-store 16 gen shards. Pollers RMW-poll their gen shard. Each block's
// thread0 then does ONE acquire load per step: the single L1/L2 invalidate that
// makes the remote-written h visible to the plain cached loads of the dot.
// Monotone counts = ABA-free. Shard populations: 150 = 6*10 + 10*9.
__device__ __forceinline__ void grid_barrier(int* __restrict__ bar, int& bno) {
    ++bno;
    __syncthreads();
    if (blockIdx.x == 0) {
        if (threadIdx.x < 64) {
            if (threadIdx.x == 0)
                __hip_atomic_fetch_add(&bar[0], 1, __ATOMIC_RELEASE, __HIP_MEMORY_SCOPE_AGENT);
            const int s = threadIdx.x;
            const int tgt = (s < 16) ? bno * ((s < 6) ? 10 : 9) : 0;
            for (;;) {
                int v = (s < 16)
                    ? __hip_atomic_fetch_add(&bar[s * 16], 0, __ATOMIC_RELAXED, __HIP_MEMORY_SCOPE_AGENT)
                    : 0x7fffffff;
                if (__all(v >= tgt)) break;
                __builtin_amdgcn_s_sleep(1);
            }
            if (threadIdx.x < 16)
                __hip_atomic_store(&bar[256 + threadIdx.x * 16], bno, __ATOMIC_RELEASE, __HIP_MEMORY_SCOPE_AGENT);
            if (threadIdx.x == 0)
                (void)__hip_atomic_load(&bar[0], __ATOMIC_ACQUIRE, __HIP_MEMORY_SCOPE_AGENT);
        }
    } else {
        if (threadIdx.x == 0) {
            __hip_atomic_fetch_add(&bar[(blockIdx.x & 15) * 16], 1, __ATOMIC_RELEASE, __HIP_MEMORY_SCOPE_AGENT);
            int* g = &bar[256 + (blockIdx.x & 15) * 16];
            while (__hip_atomic_fetch_add(g, 0, __ATOMIC_RELAXED, __HIP_MEMORY_SCOPE_AGENT) < bno)
                __builtin_amdgcn_s_sleep(1);
            (void)__hip_atomic_load(&bar[0], __ATOMIC_ACQUIRE, __HIP_MEMORY_SCOPE_AGENT);
        }
    }
    __syncthreads();
}

__global__ void init_bar(int* bar) { if (threadIdx.x < 512) bar[threadIdx.x] = 0; }

// Pack W[(g*H+j)][k] -> dst[k][j*3+g]  (k-major, gate-interleaved columns)
__global__ void build_wp(const float* __restrict__ W, float* __restrict__ dst, int kdim) {
    int idx = blockIdx.x * blockDim.x + threadIdx.x;
    if (idx >= kdim * G3) return;
    int k = idx / G3;
    int c = idx - k * G3;
    int j = c / 3;
    int g = c - j * 3;
    dst[idx] = W[(size_t)(g * H + j) * kdim + k];
}

// BC[j] = (bih_r+bhh_r, bih_z+bhh_z, bih_n, bhh_n)
__global__ void build_bc(const float* __restrict__ bih0, const float* __restrict__ bhh0,
                         const float* __restrict__ bih1, const float* __restrict__ bhh1,
                         float* __restrict__ BC0, float* __restrict__ BC1) {
    int j = blockIdx.x * blockDim.x + threadIdx.x;
    if (j >= H) return;
    BC0[j * 4 + 0] = bih0[j] + bhh0[j];
    BC0[j * 4 + 1] = bih0[H + j] + bhh0[H + j];
    BC0[j * 4 + 2] = bih0[2 * H + j];
    BC0[j * 4 + 3] = bhh0[2 * H + j];
    BC1[j * 4 + 0] = bih1[j] + bhh1[j];
    BC1[j * 4 + 1] = bih1[H + j] + bhh1[H + j];
    BC1[j * 4 + 2] = bih1[2 * H + j];
    BC1[j * 4 + 3] = bhh1[2 * H + j];
}

// Dual-batch triple dot over N4 float4s: two cached global h streams (ping-pong
// double-buffered), weight reads as float2 (ds_read_b64, conflict-free at
// KPWH=694 -- 8B-aligned rows prevent b128 re-fusion). Each weight pair feeds
// 24 FMAs across 2 batches x 3 gates.
template<int N4, int CH>
__device__ __forceinline__ void dot3x2(const float4* __restrict__ a0,
                                       const float4* __restrict__ a1,
                                       const float* wr, const float* wz, const float* wn,
                                       float& sr0, float& sz0, float& sn0,
                                       float& sr1, float& sz1, float& sn1) {
    constexpr int NCH = N4 / CH;
    static_assert(N4 % CH == 0, "chunking");
    float4 A0[CH], A1[CH], B0[CH], B1[CH];
    #pragma unroll
    for (int i = 0; i < CH; ++i) { A0[i] = a0[i]; A1[i] = a1[i]; }
    #pragma unroll 1
    for (int c = 0; c < NCH; c += 2) {
        if (c + 1 < NCH) {
            const float4* p0 = a0 + (c + 1) * CH;
            const float4* p1 = a1 + (c + 1) * CH;
            #pragma unroll
            for (int i = 0; i < CH; ++i) { B0[i] = p0[i]; B1[i] = p1[i]; }
        }
        #pragma unroll
        for (int i = 0; i < CH; ++i) {
            const int k = (c * CH + i) * 4;
            const float2 wRa = *(const float2*)(wr + k), wRb = *(const float2*)(wr + k + 2);
            const float2 wZa = *(const float2*)(wz + k), wZb = *(const float2*)(wz + k + 2);
            const float2 wNa = *(const float2*)(wn + k), wNb = *(const float2*)(wn + k + 2);
            float4 a = A0[i];
            sr0 += a.x * wRa.x + a.y * wRa.y + a.z * wRb.x + a.w * wRb.y;
            sz0 += a.x * wZa.x + a.y * wZa.y + a.z * wZb.x + a.w * wZb.y;
            sn0 += a.x * wNa.x + a.y * wNa.y + a.z * wNb.x + a.w * wNb.y;
            a = A1[i];
            sr1 += a.x * wRa.x + a.y * wRa.y + a.z * wRb.x + a.w * wRb.y;
            sz1 += a.x * wZa.x + a.y * wZa.y + a.z * wZb.x + a.w * wZb.y;
            sn1 += a.x * wNa.x + a.y * wNa.y + a.z * wNb.x + a.w * wNb.y;
        }
        if (c + 1 < NCH) {
            if (c + 2 < NCH) {
                const float4* p0 = a0 + (c + 2) * CH;
                const float4* p1 = a1 + (c + 2) * CH;
                #pragma unroll
                for (int i = 0; i < CH; ++i) { A0[i] = p0[i]; A1[i] = p1[i]; }
            }
            #pragma unroll
            for (int i = 0; i < CH; ++i) {
                const int k = ((c + 1) * CH + i) * 4;
                const float2 wRa = *(const float2*)(wr + k), wRb = *(const float2*)(wr + k + 2);
                const float2 wZa = *(const float2*)(wz + k), wZb = *(const float2*)(wz + k + 2);
                const float2 wNa = *(const float2*)(wn + k), wNb = *(const float2*)(wn + k + 2);
                float4 a = B0[i];
                sr0 += a.x * wRa.x + a.y * wRa.y + a.z * wRb.x + a.w * wRb.y;
                sz0 += a.x * wZa.x + a.y * wZa.y + a.z * wZb.x + a.w * wZb.y;
                sn0 += a.x * wNa.x + a.y * wNa.y + a.z * wNb.x + a.w * wNb.y;
                a = B1[i];
                sr1 += a.x * wRa.x + a.y * wRa.y + a.z * wRb.x + a.w * wRb.y;
                sz1 += a.x * wZa.x + a.y * wZa.y + a.z * wZb.x + a.w * wZb.y;
                sn1 += a.x * wNa.x + a.y * wNa.y + a.z * wNb.x + a.w * wNb.y;
            }
        }
    }
}

// Input-GEMM inner: 8 consecutive t-rows of one batch vs this thread's 3 gate
// columns. Wi b128 reads are 4-base broadcast (conflict-free); x ping-pong.
template<int KIN>
__device__ __forceinline__ void gemm8(const float* xb,
                                      const float* wr, const float* wz, const float* wn,
                                      float* aR, float* aZ, float* aN) {
    constexpr int N4 = KIN / 4;
    float4 X[8], Y[8];
    #pragma unroll
    for (int i = 0; i < 8; ++i) X[i] = *(const float4*)(xb + (size_t)i * KIN);
    #pragma unroll 1
    for (int c = 0; c < N4; c += 2) {
        if (c + 1 < N4) {
            #pragma unroll
            for (int i = 0; i < 8; ++i) Y[i] = *(const float4*)(xb + (size_t)i * KIN + (c + 1) * 4);
        }
        {
            const int k = c * 4;
            const float4 wR = *(const float4*)(wr + k);
            const float4 wZ = *(const float4*)(wz + k);
            const float4 wN = *(const float4*)(wn + k);
            #pragma unroll
            for (int i = 0; i < 8; ++i) {
                const float4 a = X[i];
                aR[i] += a.x * wR.x + a.y * wR.y + a.z * wR.z + a.w * wR.w;
                aZ[i] += a.x * wZ.x + a.y * wZ.y + a.z * wZ.z + a.w * wZ.w;
                aN[i] += a.x * wN.x + a.y * wN.y + a.z * wN.z + a.w * wN.w;
            }
        }
        if (c + 1 < N4) {
            if (c + 2 < N4) {
                #pragma unroll
                for (int i = 0; i < 8; ++i) X[i] = *(const float4*)(xb + (size_t)i * KIN + (c + 2) * 4);
            }
            const int k = (c + 1) * 4;
            const float4 wR = *(const float4*)(wr + k);
            const float4 wZ = *(const float4*)(wz + k);
            const float4 wN = *(const float4*)(wn + k);
            #pragma unroll
            for (int i = 0; i < 8; ++i) {
                const float4 a = Y[i];
                aR[i] += a.x * wR.x + a.y * wR.y + a.z * wR.z + a.w * wR.w;
                aZ[i] += a.x * wZ.x + a.y * wZ.y + a.z * wZ.z + a.w * wZ.w;
                aN[i] += a.x * wN.x + a.y * wN.y + a.z * wN.z + a.w * wN.w;
            }
        }
    }
}

// x and ret may alias (layer 1) -> both non-restrict.
template<int LAYER>
__device__ void gru_layer(const float* x, const float* __restrict__ hid,
                          const float* __restrict__ WIp, const float* __restrict__ WHp,
                          const float* __restrict__ BC,
                          float* __restrict__ hA, float* __restrict__ hB,
                          float* __restrict__ gi, float* ret, float* __restrict__ outh,
                          float* Wi, float* Wh, int* bar, int& bno) {
    constexpr int KIN  = LAYER ? H : IN0;
    constexpr int KPWI = LAYER ? KPW1 : KPW0;
    const int tid = threadIdx.x;
    const int jj = tid & 3;            // j column within block
    const int kh = (tid >> 2) & 3;     // K-quarter (scan); (batch-half, octet) in GEMM
    const int bp = tid >> 4;           // batch pair 0..31: batches {bp, bp+32}
    const int b0 = bp, b1 = bp + 32;
    const int j  = blockIdx.x * 4 + jj;
    const int wcol0 = blockIdx.x * 12;
    const int bg  = bp + (kh >> 1) * 32;   // GEMM batch 0..63
    const int oct = kh & 1;                // GEMM t-row octet

    // Stage this block's 12 W_ih and 12 zero-padded W_hh gate-columns into LDS.
    for (int idx = tid; idx < 12 * KIN; idx += NTHR) {
        int k = idx / 12, c = idx - k * 12;
        Wi[c * KPWI + k] = WIp[(size_t)k * G3 + wcol0 + c];
    }
    for (int idx = tid; idx < 12 * KP; idx += NTHR) {
        int k = idx / 12, c = idx - k * 12;
        Wh[c * KPWH + k] = (k < H) ? WHp[(size_t)k * G3 + wcol0 + c] : 0.f;
    }
    // h buffers, padded layout [B][KP]; pads MUST be finite (they hit zero weights).
    for (int idx = blockIdx.x * NTHR + tid; idx < B * KP; idx += NBLK * NTHR) {
        int bb = idx / KP, col = idx - bb * KP;
        float v = (col < H) ? hid[bb * H + col] : 0.f;
        __builtin_nontemporal_store(v, &hA[idx]);
        __builtin_nontemporal_store(v, &hB[idx]);
    }
    grid_barrier(bar, bno);   // covers LDS staging + h init

    const float4 bc = *(const float4*)(BC + j * 4);
    const float* wrI = &Wi[(jj * 3 + 0) * KPWI];
    const float* wzI = &Wi[(jj * 3 + 1) * KPWI];
    const float* wnI = &Wi[(jj * 3 + 2) * KPWI];
    const float* wrH = &Wh[(jj * 3 + 0) * KPWH + kh * KQ];
    const float* wzH = &Wh[(jj * 3 + 1) * KPWH + kh * KQ];
    const float* wnH = &Wh[(jj * 3 + 2) * KPWH + kh * KQ];

    float hv0 = hid[b0 * H + j];       // recurrent state (kh==0 lanes maintain)
    float hv1 = hid[b1 * H + j];
    float hold0 = 0.f, hold1 = 0.f;    // LAYER 1 lag-write holds

    float* hc = hA;
    float* hn = hB;

    #pragma unroll 1
    for (int ch = 0; ch < NCHUNK; ++ch) {
        const int t0 = ch * TCH;

        // ---- gi GEMM phase: all 512 threads; batch bg, rows t0+oct*8..+7 ----
        {
            float aR[8], aZ[8], aN[8];
            #pragma unroll
            for (int i = 0; i < 8; ++i) { aR[i] = 0.f; aZ[i] = 0.f; aN[i] = 0.f; }
            const float* xb = x + ((size_t)bg * T + t0 + oct * 8) * KIN;
            gemm8<KIN>(xb, wrI, wzI, wnI, aR, aZ, aN);
            #pragma unroll
            for (int i = 0; i < 8; ++i) {
                float4 o;
                o.x = aR[i] + bc.x;   // r pre-activation + both r biases
                o.y = aZ[i] + bc.y;   // z pre-activation + both z biases
                o.z = aN[i] + bc.z;   // n x-part + bih_n
                o.w = bc.w;           // bhh_n (added inside r*(.) in scan)
                *(float4*)(gi + ((size_t)((oct * 8 + i) * B + bg) * H + j) * 4) = o;
            }
        }
        // gi for (b, j) written and read by the SAME block -> block barrier only.
        __syncthreads();

        // ---- scan: 16 sequential steps; thread = 2 batches x K-quarter ----
        #pragma unroll 1
        for (int tl = 0; tl < TCH; ++tl) {
            const int t = t0 + tl;
            float4 g40, g41;
            if (kh == 0) {
                g40 = *(const float4*)(gi + ((size_t)(tl * B + b0) * H + j) * 4);
                g41 = *(const float4*)(gi + ((size_t)(tl * B + b1) * H + j) * 4);
            }
            float sr0 = 0.f, sz0 = 0.f, sn0 = 0.f, sr1 = 0.f, sz1 = 0.f, sn1 = 0.f;
            dot3x2<KQ / 4, 6>((const float4*)(hc + (size_t)b0 * KP + kh * KQ),
                              (const float4*)(hc + (size_t)b1 * KP + kh * KQ),
                              wrH, wzH, wnH, sr0, sz0, sn0, sr1, sz1, sn1);
            // combine K-quarters: kh sits in lane bits 2-3 -> butterfly xor 4, 8
            sr0 += __shfl_xor(sr0, 4); sr0 += __shfl_xor(sr0, 8);
            sz0 += __shfl_xor(sz0, 4); sz0 += __shfl_xor(sz0, 8);
            sn0 += __shfl_xor(sn0, 4); sn0 += __shfl_xor(sn0, 8);
            sr1 += __shfl_xor(sr1, 4); sr1 += __shfl_xor(sr1, 8);
            sz1 += __shfl_xor(sz1, 4); sz1 += __shfl_xor(sz1, 8);
            sn1 += __shfl_xor(sn1, 4); sn1 += __shfl_xor(sn1, 8);
            if (kh == 0) {
                float r0 = 1.f / (1.f + __expf(-(sr0 + g40.x)));
                float z0 = 1.f / (1.f + __expf(-(sz0 + g40.y)));
                float n0 = tanhf(g40.z + r0 * (sn0 + g40.w));
                hv0 = (1.f - z0) * n0 + z0 * hv0;
                __builtin_nontemporal_store(hv0, &hn[(size_t)b0 * KP + j]);
                float r1 = 1.f / (1.f + __expf(-(sr1 + g41.x)));
                float z1 = 1.f / (1.f + __expf(-(sz1 + g41.y)));
                float n1 = tanhf(g41.z + r1 * (sn1 + g41.w));
                hv1 = (1.f - z1) * n1 + z1 * hv1;
                __builtin_nontemporal_store(hv1, &hn[(size_t)b1 * KP + j]);
                if (LAYER == 0) {
                    __builtin_nontemporal_store(hv0, &ret[((size_t)b0 * T + t) * H + j]);
                    __builtin_nontemporal_store(hv1, &ret[((size_t)b1 * T + t) * H + j]);
                } else {
                    // lag-write: row t-1 was GEMM-read >= one barrier+dot ago
                    if (t > 0) {
                        __builtin_nontemporal_store(hold0, &ret[((size_t)b0 * T + (t - 1)) * H + j]);
                        __builtin_nontemporal_store(hold1, &ret[((size_t)b1 * T + (t - 1)) * H + j]);
                    }
                    hold0 = hv0; hold1 = hv1;
                }
            }
            grid_barrier(bar, bno);   // h all-to-all exchange (incl. per-step acquire)
            float* tmp = hc; hc = hn; hn = tmp;
        }
    }
    if (kh == 0) {
        if (LAYER == 1) {
            __builtin_nontemporal_store(hold0, &ret[((size_t)b0 * T + (T - 1)) * H + j]);
            __builtin_nontemporal_store(hold1, &ret[((size_t)b1 * T + (T - 1)) * H + j]);
        }
        __builtin_nontemporal_store(hv0, &outh[b0 * H + j]);
        __builtin_nontemporal_store(hv1, &outh[b1 * H + j]);
    }
    grid_barrier(bar, bno);   // ret complete before next layer's GEMM reads it
}

__global__ void __launch_bounds__(NTHR, 2) gru_main(
    const float* x0, const float* __restrict__ hid,
    const float* __restrict__ WI0, const float* __restrict__ WH0,
    const float* __restrict__ WI1, const float* __restrict__ WH1,
    const float* __restrict__ BC0, const float* __restrict__ BC1,
    float* __restrict__ hA, float* __restrict__ hB, float* __restrict__ gi,
    float* ret, float* __restrict__ outh, int* bar) {
    __shared__ __align__(16) float Wi[12 * KPW1];   // 28,800 B (L0 uses stride KPW0)
    __shared__ __align__(16) float Wh[12 * KPWH];   // 33,312 B -> total 62,112 B
    int bno = 0;
    gru_layer<0>(x0,  hid,         WI0, WH0, BC0, hA, hB, gi, ret, outh,         Wi, Wh, bar, bno);
    gru_layer<1>(ret, hid + B * H, WI1, WH1, BC1, hA, hB, gi, ret, outh + B * H, Wi, Wh, bar, bno);
}

extern "C" void kernel_launch(void* const* d_in, const int* in_sizes, int n_in,
                              void* d_out, int out_size, void* d_ws, size_t ws_size,
                              hipStream_t stream) {
    const float* x0   = (const float*)d_in[0];
    const float* hid  = (const float*)d_in[1];
    const float* Wih0 = (const float*)d_in[2];
    const float* Whh0 = (const float*)d_in[3];
    const float* bih0 = (const float*)d_in[4];
    const float* bhh0 = (const float*)d_in[5];
    const float* Wih1 = (const float*)d_in[6];
    const float* Whh1 = (const float*)d_in[7];
    const float* bih1 = (const float*)d_in[8];
    const float* bhh1 = (const float*)d_in[9];

    float* ws  = (float*)d_ws;
    float* WI0 = ws + WI0_OFF;
    float* WH0 = ws + WH0_OFF;
    float* WI1 = ws + WI1_OFF;
    float* WH1 = ws + WH1_OFF;
    float* BC0 = ws + BC0_OFF;
    float* BC1 = ws + BC1_OFF;
    float* hA  = ws + HA_OFF;
    float* hB  = ws + HB_OFF;
    float* gi  = ws + GI_OFF;
    int*   bar = (int*)(ws + BAR_OFF);

    float* ret  = (float*)d_out;
    float* outh = ret + (size_t)B * T * H;

    build_wp<<<(IN0 * G3 + 255) / 256, 256, 0, stream>>>(Wih0, WI0, IN0);
    build_wp<<<(H * G3 + 255) / 256, 256, 0, stream>>>(Whh0, WH0, H);
    build_wp<<<(H * G3 + 255) / 256, 256, 0, stream>>>(Wih1, WI1, H);
    build_wp<<<(H * G3 + 255) / 256, 256, 0, stream>>>(Whh1, WH1, H);
    build_bc<<<(H + 255) / 256, 256, 0, stream>>>(bih0, bhh0, bih1, bhh1, BC0, BC1);
    init_bar<<<1, 512, 0, stream>>>(bar);

    gru_main<<<dim3(NBLK), dim3(NTHR), 0, stream>>>(
        x0, hid, WI0, WH0, WI1, WH1, BC0, BC1, hA, hB, gi, ret, outh, bar);
}